// Round 3
// baseline (116.485 us; speedup 1.0000x reference)
//
#include <hip/hip_runtime.h>
#include <stdint.h>

typedef __attribute__((ext_vector_type(8))) short short8;       // 8 x bf16
typedef __attribute__((ext_vector_type(4))) float f32x4;
typedef __attribute__((ext_vector_type(4))) unsigned short ushort4_;
typedef __attribute__((ext_vector_type(4))) unsigned int uint4_;

#define MFMA16(a, b, c) __builtin_amdgcn_mfma_f32_16x16x32_bf16((a), (b), (c), 0, 0, 0)

static __device__ __forceinline__ unsigned short f2bf(float f) {
    unsigned u = __float_as_uint(f);
    u += 0x7fffu + ((u >> 16) & 1u);   // RNE
    return (unsigned short)(u >> 16);
}

static __device__ __forceinline__ float exp2_fast(float x) {
#if __has_builtin(__builtin_amdgcn_exp2f)
    return __builtin_amdgcn_exp2f(x);
#else
    return exp2f(x);
#endif
}

static __device__ __forceinline__ unsigned cvt_pk(float lo, float hi) {
    unsigned r;
    asm("v_cvt_pk_bf16_f32 %0, %1, %2" : "=v"(r) : "v"(lo), "v"(hi));
    return r;
}

static __device__ __forceinline__ short8 pack8(float a0, float a1, float a2, float a3,
                                               float a4, float a5, float a6, float a7) {
    union { uint4_ u; short8 s; } c;
    c.u[0] = cvt_pk(a0, a1); c.u[1] = cvt_pk(a2, a3);
    c.u[2] = cvt_pk(a4, a5); c.u[3] = cvt_pk(a6, a7);
    return c.s;
}

#define GLOAD16(SRC, DSTPTR) __builtin_amdgcn_global_load_lds(                       \
    (const __attribute__((address_space(1))) void*)(SRC),                            \
    (__attribute__((address_space(3))) void*)(DSTPTR), 16, 0, 0)

// ---------------------------------------------------------------------------
// Kernel 0: W (3 heads, f32) -> bf16, contiguous Wb[3][128][1024]
// ---------------------------------------------------------------------------
__global__ __launch_bounds__(256) void wcvt_kernel(
    const float* __restrict__ Wq, const float* __restrict__ Wk, const float* __restrict__ Wv,
    unsigned short* __restrict__ Wb)
{
    const int hd = blockIdx.y;
    const float* W = (hd == 0) ? Wq : ((hd == 1) ? Wk : Wv);
    const int idx = (blockIdx.x * 256 + threadIdx.x) * 4;
    f32x4 v = *(const f32x4*)(W + idx);
    ushort4_ o;
#pragma unroll
    for (int j = 0; j < 4; ++j) o[j] = f2bf(v[j]);
    *(ushort4_*)(Wb + (size_t)hd * 131072 + idx) = o;
}

// ---------------------------------------------------------------------------
// Kernel 1: fused QKV. One block = 64 X-rows, ALL 3 heads (X read once).
// 4 waves x 6 col-frag-groups (cfg = head*8+cf, 24 total). W bf16 fragments
// direct from global (reg dbuf); X tile staged bf16 in LDS, 2-step pipeline.
//   head0: Q * log2(e)/sqrt(128) -> Qs ; head1: K -> Kb ; head2: V -> Vt^T
// ---------------------------------------------------------------------------
__global__ __launch_bounds__(256, 1) void qkv_kernel(
    const float* __restrict__ X, const unsigned short* __restrict__ Wb,
    unsigned short* __restrict__ Qs, unsigned short* __restrict__ Kb, unsigned short* __restrict__ Vt)
{
    __shared__ __align__(16) char lds[8192];
    const int tid = threadIdx.x, lane = tid & 63, wid = tid >> 6;
    const int lrow = lane & 15, lgrp = lane >> 4;
    const int m0 = blockIdx.x * 64;

    const int xrow = tid >> 2, xseg = tid & 3;
    const int xsw = (xrow & 7) << 4;
    const float* xbase = X + (size_t)(m0 + xrow) * 1024 + xseg * 16;

    const unsigned short* wp[6];
#pragma unroll
    for (int i = 0; i < 6; ++i) {
        const int cfg = wid * 6 + i;
        wp[i] = Wb + (size_t)(cfg >> 3) * 131072 + (size_t)((cfg & 7) * 16 + lrow) * 1024 + lgrp * 8;
    }

    f32x4 acc[4][6];
#pragma unroll
    for (int mi = 0; mi < 4; ++mi)
#pragma unroll
        for (int i = 0; i < 6; ++i) acc[mi][i] = (f32x4)0.0f;

    f32x4 xr[4];
    short8 wa[6][2], wb2[6][2];

    // prologue: X(0) -> regs -> LDS; W(0) -> wa; X(1) -> regs
#pragma unroll
    for (int u = 0; u < 4; ++u) xr[u] = *(const f32x4*)(xbase + u * 4);
#pragma unroll
    for (int i = 0; i < 6; ++i) {
        wa[i][0] = *(const short8*)(wp[i]);
        wa[i][1] = *(const short8*)(wp[i] + 32);
    }
    {
        short8 p0 = pack8(xr[0][0], xr[0][1], xr[0][2], xr[0][3], xr[1][0], xr[1][1], xr[1][2], xr[1][3]);
        short8 p1 = pack8(xr[2][0], xr[2][1], xr[2][2], xr[2][3], xr[3][0], xr[3][1], xr[3][2], xr[3][3]);
        *(short8*)(lds + xrow * 128 + ((xseg * 32) ^ xsw)) = p0;
        *(short8*)(lds + xrow * 128 + ((xseg * 32 + 16) ^ xsw)) = p1;
    }
#pragma unroll
    for (int u = 0; u < 4; ++u) xr[u] = *(const f32x4*)(xbase + 64 + u * 4);
    __syncthreads();

#define QKV_STEP(WC, WN, S)                                                          \
    do {                                                                             \
        if ((S) < 15) {                                                              \
            _Pragma("unroll")                                                        \
            for (int i = 0; i < 6; ++i) {                                            \
                WN[i][0] = *(const short8*)(wp[i] + ((S) + 1) * 64);                 \
                WN[i][1] = *(const short8*)(wp[i] + ((S) + 1) * 64 + 32);            \
            }                                                                        \
        }                                                                            \
        __builtin_amdgcn_s_setprio(1);                                               \
        _Pragma("unroll")                                                            \
        for (int kc = 0; kc < 2; ++kc) {                                             \
            short8 a[4];                                                             \
            _Pragma("unroll")                                                        \
            for (int mi = 0; mi < 4; ++mi)                                           \
                a[mi] = *(const short8*)(lds + (mi * 16 + lrow) * 128 +              \
                          ((kc * 64 + lgrp * 16) ^ ((lrow & 7) << 4)));              \
            _Pragma("unroll")                                                        \
            for (int i = 0; i < 6; ++i)                                              \
                _Pragma("unroll")                                                    \
                for (int mi = 0; mi < 4; ++mi)                                       \
                    acc[mi][i] = MFMA16(a[mi], WC[i][kc], acc[mi][i]);               \
        }                                                                            \
        __builtin_amdgcn_s_setprio(0);                                               \
        if ((S) < 15) {                                                              \
            __syncthreads();                                                         \
            short8 p0 = pack8(xr[0][0], xr[0][1], xr[0][2], xr[0][3],                \
                              xr[1][0], xr[1][1], xr[1][2], xr[1][3]);               \
            short8 p1 = pack8(xr[2][0], xr[2][1], xr[2][2], xr[2][3],                \
                              xr[3][0], xr[3][1], xr[3][2], xr[3][3]);               \
            *(short8*)(lds + xrow * 128 + ((xseg * 32) ^ xsw)) = p0;                 \
            *(short8*)(lds + xrow * 128 + ((xseg * 32 + 16) ^ xsw)) = p1;            \
            if ((S) < 14) {                                                          \
                _Pragma("unroll")                                                    \
                for (int u = 0; u < 4; ++u)                                          \
                    xr[u] = *(const f32x4*)(xbase + ((S) + 2) * 64 + u * 4);         \
            }                                                                        \
            __syncthreads();                                                         \
        }                                                                            \
    } while (0)

#pragma unroll
    for (int ss = 0; ss < 8; ++ss) {
        QKV_STEP(wa, wb2, 2 * ss);
        QKV_STEP(wb2, wa, 2 * ss + 1);
    }
#undef QKV_STEP

    const float qscale = 0.12752039f;   // log2(e)/sqrt(128)
#pragma unroll
    for (int i = 0; i < 6; ++i) {
        const int cfg = wid * 6 + i;
        const int head = cfg >> 3, cf = cfg & 7;
        if (head < 2) {
            unsigned short* dst = (head == 0) ? Qs : Kb;
            const float sc = (head == 0) ? qscale : 1.0f;
#pragma unroll
            for (int mi = 0; mi < 4; ++mi)
#pragma unroll
                for (int r = 0; r < 4; ++r) {
                    const int row = m0 + mi * 16 + lgrp * 4 + r;
                    dst[(size_t)row * 128 + cf * 16 + lrow] = f2bf(acc[mi][i][r] * sc);
                }
        } else {
#pragma unroll
            for (int mi = 0; mi < 4; ++mi) {
                ushort4_ v;
#pragma unroll
                for (int r = 0; r < 4; ++r) v[r] = f2bf(acc[mi][i][r]);
                *(ushort4_*)(Vt + (size_t)(cf * 16 + lrow) * 8192 + m0 + mi * 16 + lgrp * 4) = v;
            }
        }
    }
}

// ---------------------------------------------------------------------------
// Kernel 2: flash-attention partial.
// grid 512 = 128 q-tiles(64) x 4 kv-splits(2048). Block 256thr = 4 waves =
// 2 qh(32 q each) x 2 kvlane(1024 kv each). KVBLK=32, 32 iters.
// K: global_load_lds w16 into dbuf LDS, sigma-permuted + XOR-swizzled SOURCE.
// V: direct global->reg fragments (no LDS). One barrier per iter.
// In-block 2-way kv merge; 4 global partials.
// ---------------------------------------------------------------------------
__global__ __launch_bounds__(256, 2) void attn_kernel(
    const unsigned short* __restrict__ Qs,
    const unsigned short* __restrict__ Kb,
    const unsigned short* __restrict__ Vt,
    float* __restrict__ partO, float* __restrict__ partML)
{
    __shared__ __align__(16) char lds[66048];  // K dbuf 32KB | merge 2x16640
    const int tid = threadIdx.x, lane = tid & 63, wid = tid >> 6;
    const int lrow = lane & 15, lgrp = lane >> 4;
    const int kvl = wid & 1, qh = wid >> 1;
    const int qtile = blockIdx.x >> 2, sp = blockIdx.x & 3;  // sp const per XCD
    const int qb = qtile * 64 + qh * 32;
    const int kvstart = sp * 2048 + kvl * 1024;

    // --- K staging: per-lane swizzled global source, linear LDS dest ---
    const char* kbyte = (const char*)Kb;
    const char* ksrc[4];
    char* kdst[4];
#pragma unroll
    for (int c = 0; c < 4; ++c) {
        const int slot = (qh * 4 + c) * 4 + (lane >> 4);
        const int krow = ((slot >> 2) & 3) * 8 + ((slot >> 4) & 1) * 4 + (slot & 3);
        const int off  = ((lane & 15) * 16) ^ ((slot & 15) << 4);
        ksrc[c] = kbyte + (size_t)(kvstart + krow) * 256 + off;
        kdst[c] = lds + kvl * 16384 + (qh * 4 + c) * 1024;     // + buf*8192
    }
    // --- V fragment base (direct global) ---
    const char* vbyte = (const char*)Vt + (size_t)lrow * 16384 + (size_t)kvstart * 2 + lgrp * 16;

    // Q fragments: lane holds Q[qb + j*16 + lrow][c*32 + lgrp*8 ..]
    short8 qf[2][4];
#pragma unroll
    for (int j = 0; j < 2; ++j)
#pragma unroll
        for (int c = 0; c < 4; ++c)
            qf[j][c] = *(const short8*)(Qs + (size_t)(qb + j * 16 + lrow) * 128 + c * 32 + lgrp * 8);

    f32x4 o[2][8];
#pragma unroll
    for (int j = 0; j < 2; ++j)
#pragma unroll
        for (int i = 0; i < 8; ++i) o[j][i] = (f32x4)0.0f;
    float m[2] = { -1e30f, -1e30f }, l[2] = { 0.0f, 0.0f };

    // prologue: K(0) -> buf 0
#pragma unroll
    for (int c = 0; c < 4; ++c) GLOAD16(ksrc[c], kdst[c]);
    asm volatile("s_waitcnt vmcnt(0)" ::: "memory");
    __syncthreads();

    for (int t = 0; t < 32; ++t) {
        const int buf = t & 1;
        if (t < 31) {   // K(t+1) -> other buffer; in flight across this iter
#pragma unroll
            for (int c = 0; c < 4; ++c)
                GLOAD16(ksrc[c] + (size_t)(t + 1) * 8192, kdst[c] + (buf ^ 1) * 8192);
        }
        short8 vr[8];   // V fragments for tile t, direct from global (L2)
#pragma unroll
        for (int df = 0; df < 8; ++df)
            vr[df] = *(const short8*)(vbyte + (size_t)df * 262144 + t * 64);

        const char* kb = lds + kvl * 16384 + buf * 8192;

        // ---- S^T = K Q (exp2 domain; scale folded into Q) ----
        f32x4 s[2][2];
        s[0][0] = s[0][1] = s[1][0] = s[1][1] = (f32x4)0.0f;
        __builtin_amdgcn_s_setprio(1);
#pragma unroll
        for (int f = 0; f < 2; ++f) {
            const int rbase = (f * 16 + lrow) * 256;
            const int swz = lrow << 4;
#pragma unroll
            for (int c = 0; c < 4; ++c) {
                short8 kf = *(const short8*)(kb + rbase + ((c * 64 + lgrp * 16) ^ swz));
                s[0][f] = MFMA16(kf, qf[0][c], s[0][f]);
                s[1][f] = MFMA16(kf, qf[1][c], s[1][f]);
            }
        }
        __builtin_amdgcn_s_setprio(0);

        // ---- online softmax: lane owns q=lane&15 (per j), kv = 8*lgrp+4f+r ----
        float tm[2];
#pragma unroll
        for (int j = 0; j < 2; ++j) {
            float t0 = fmaxf(fmaxf(s[j][0][0], s[j][0][1]), fmaxf(s[j][0][2], s[j][0][3]));
            float t1 = fmaxf(fmaxf(s[j][1][0], s[j][1][1]), fmaxf(s[j][1][2], s[j][1][3]));
            float t2 = fmaxf(t0, t1);
            t2 = fmaxf(t2, __shfl_xor(t2, 16));
            t2 = fmaxf(t2, __shfl_xor(t2, 32));
            tm[j] = t2;
        }
        const bool need = (tm[0] > m[0] + 8.0f) || (tm[1] > m[1] + 8.0f);
        if (__any(need)) {   // deferred-max rescale
#pragma unroll
            for (int j = 0; j < 2; ++j) {
                const float mn = fmaxf(m[j], tm[j]);
                const float al = exp2_fast(m[j] - mn);
                m[j] = mn;
                l[j] *= al;
#pragma unroll
                for (int r = 0; r < 4; ++r) {
                    const float ar = __shfl(al, lgrp * 4 + r);
#pragma unroll
                    for (int df = 0; df < 8; ++df) o[j][df][r] *= ar;
                }
            }
        }
        short8 pa[2];
#pragma unroll
        for (int j = 0; j < 2; ++j) {
            const float p0 = exp2_fast(s[j][0][0] - m[j]);
            const float p1 = exp2_fast(s[j][0][1] - m[j]);
            const float p2 = exp2_fast(s[j][0][2] - m[j]);
            const float p3 = exp2_fast(s[j][0][3] - m[j]);
            const float p4 = exp2_fast(s[j][1][0] - m[j]);
            const float p5 = exp2_fast(s[j][1][1] - m[j]);
            const float p6 = exp2_fast(s[j][1][2] - m[j]);
            const float p7 = exp2_fast(s[j][1][3] - m[j]);
            float rs = ((p0 + p1) + (p2 + p3)) + ((p4 + p5) + (p6 + p7));
            rs += __shfl_xor(rs, 16);
            rs += __shfl_xor(rs, 32);
            l[j] += rs;
            pa[j] = pack8(p0, p1, p2, p3, p4, p5, p6, p7);
        }

        // ---- O += P V  (vr waits drain all VMEM incl. K glds before barrier) ----
        __builtin_amdgcn_s_setprio(1);
#pragma unroll
        for (int df = 0; df < 8; ++df) {
            o[0][df] = MFMA16(pa[0], vr[df], o[0][df]);
            o[1][df] = MFMA16(pa[1], vr[df], o[1][df]);
        }
        __builtin_amdgcn_s_setprio(0);
        __syncthreads();
    }

    // ---- own state to row form (row = j*16 + lgrp*4 + r) ----
    float mr[2][4], lr_[2][4];
#pragma unroll
    for (int j = 0; j < 2; ++j)
#pragma unroll
        for (int r = 0; r < 4; ++r) {
            mr[j][r]  = __shfl(m[j], lgrp * 4 + r);
            lr_[j][r] = __shfl(l[j], lgrp * 4 + r);
        }

    // ---- in-block 2-way kv merge ----
    if (kvl == 1) {
        char* mb = lds + 32768 + qh * 16640;
#pragma unroll
        for (int j = 0; j < 2; ++j)
#pragma unroll
            for (int df = 0; df < 8; ++df)
#pragma unroll
                for (int r = 0; r < 4; ++r)
                    *(float*)(mb + (j * 16 + lgrp * 4 + r) * 512 + (df * 16 + lrow) * 4) = o[j][df][r];
        if (lgrp == 0) {
#pragma unroll
            for (int j = 0; j < 2; ++j) {
                *(float*)(mb + 16384 + (j * 16 + lrow) * 8)     = m[j];
                *(float*)(mb + 16384 + (j * 16 + lrow) * 8 + 4) = l[j];
            }
        }
    }
    __syncthreads();
    if (kvl == 0) {
        char* mb = lds + 32768 + qh * 16640;
#pragma unroll
        for (int j = 0; j < 2; ++j)
#pragma unroll
            for (int r = 0; r < 4; ++r) {
                const int qrow = j * 16 + lgrp * 4 + r;
                const float pm = *(float*)(mb + 16384 + qrow * 8);
                const float pl = *(float*)(mb + 16384 + qrow * 8 + 4);
                const float M = fmaxf(mr[j][r], pm);
                const float a = exp2_fast(mr[j][r] - M);
                const float b = exp2_fast(pm - M);
                lr_[j][r] = lr_[j][r] * a + pl * b;
                mr[j][r] = M;
#pragma unroll
                for (int df = 0; df < 8; ++df) {
                    const float po = *(float*)(mb + qrow * 512 + (df * 16 + lrow) * 4);
                    o[j][df][r] = o[j][df][r] * a + po * b;
                }
            }
        // ---- write unnormalized partial + (m,l) ----
#pragma unroll
        for (int j = 0; j < 2; ++j)
#pragma unroll
            for (int df = 0; df < 8; ++df)
#pragma unroll
                for (int r = 0; r < 4; ++r) {
                    const int qg = qb + j * 16 + lgrp * 4 + r;
                    partO[((size_t)sp * 8192 + qg) * 128 + df * 16 + lrow] = o[j][df][r];
                }
        if (lrow == 0) {
#pragma unroll
            for (int j = 0; j < 2; ++j)
#pragma unroll
                for (int r = 0; r < 4; ++r) {
                    const int qg = qb + j * 16 + lgrp * 4 + r;
                    partML[((size_t)sp * 8192 + qg) * 2]     = mr[j][r];
                    partML[((size_t)sp * 8192 + qg) * 2 + 1] = lr_[j][r];
                }
        }
    }
}

// ---------------------------------------------------------------------------
// Kernel 3: merge 4 kv-split partials and normalize.
// ---------------------------------------------------------------------------
__global__ __launch_bounds__(256) void merge_kernel(
    const float* __restrict__ partO, const float* __restrict__ partML, float* __restrict__ out)
{
    const int gid = blockIdx.x * 256 + threadIdx.x;   // 0..262143
    const int q = gid >> 5, dc = gid & 31;
    float mv[4], lv[4];
#pragma unroll
    for (int spv = 0; spv < 4; ++spv) {
        mv[spv] = partML[((size_t)spv * 8192 + q) * 2];
        lv[spv] = partML[((size_t)spv * 8192 + q) * 2 + 1];
    }
    const float M = fmaxf(fmaxf(mv[0], mv[1]), fmaxf(mv[2], mv[3]));
    float e[4], L = 0.f;
#pragma unroll
    for (int spv = 0; spv < 4; ++spv) { e[spv] = exp2_fast(mv[spv] - M); L += lv[spv] * e[spv]; }
    const float inv = 1.0f / L;
    f32x4 r = (f32x4)0.0f;
#pragma unroll
    for (int spv = 0; spv < 4; ++spv) {
        f32x4 v = *(const f32x4*)(partO + ((size_t)spv * 8192 + q) * 128 + dc * 4);
#pragma unroll
        for (int k = 0; k < 4; ++k) r[k] += v[k] * e[spv];
    }
#pragma unroll
    for (int k = 0; k < 4; ++k) r[k] *= inv;
    *(f32x4*)(out + (size_t)q * 128 + dc * 4) = r;
}

extern "C" void kernel_launch(void* const* d_in, const int* in_sizes, int n_in,
                              void* d_out, int out_size, void* d_ws, size_t ws_size,
                              hipStream_t stream)
{
    const float* X  = (const float*)d_in[0];
    const float* Wq = (const float*)d_in[1];
    const float* Wk = (const float*)d_in[2];
    const float* Wv = (const float*)d_in[3];

    char* ws = (char*)d_ws;
    const size_t QS_OFF  = 0;                                   // 2 MiB
    const size_t KB_OFF  = QS_OFF + (size_t)8192 * 128 * 2;     // 2 MiB
    const size_t VT_OFF  = KB_OFF + (size_t)8192 * 128 * 2;     // 2 MiB (V transposed)
    const size_t WB_OFF  = VT_OFF + (size_t)8192 * 128 * 2;     // 768 KiB
    const size_t PO_OFF  = WB_OFF + (size_t)3 * 128 * 1024 * 2; // 4*8192*128 f32 = 16 MiB
    const size_t PML_OFF = PO_OFF + (size_t)4 * 8192 * 128 * 4; // 4*8192*2 f32 = 256 KiB

    unsigned short* Qs  = (unsigned short*)(ws + QS_OFF);
    unsigned short* Kb  = (unsigned short*)(ws + KB_OFF);
    unsigned short* Vt  = (unsigned short*)(ws + VT_OFF);
    unsigned short* Wb  = (unsigned short*)(ws + WB_OFF);
    float* partO  = (float*)(ws + PO_OFF);
    float* partML = (float*)(ws + PML_OFF);
    float* out = (float*)d_out;

    wcvt_kernel<<<dim3(128, 3), 256, 0, stream>>>(Wq, Wk, Wv, Wb);
    qkv_kernel<<<dim3(128), 256, 0, stream>>>(X, Wb, Qs, Kb, Vt);
    attn_kernel<<<dim3(512), 256, 0, stream>>>(Qs, Kb, Vt, partO, partML);
    merge_kernel<<<dim3(1024), 256, 0, stream>>>(partO, partML, out);
}